// Round 1
// baseline (136.397 us; speedup 1.0000x reference)
//
#include <hip/hip_runtime.h>

// ---------------------------------------------------------------------------
// 3-dispatch gather splat, 8^3 tiles, one wave per tile, FAT LIST ENTRIES.
// R7: bin_prep precomputes EVERYTHING per (gaussian,tile) pair into a 64B
// record: 64-bit (y,z) lane mask, cy/cz/w2, and the clipped+intensity-folded
// 8-tap x-table. Hot loop = 1 prefetched scalar load + ~36 VALU cycles.
// R8 (this round): bin_prep was 784 waves on 1024 SIMDs (0.77 waves/SIMD) with
// a dependent atomicAdd->store chain per tile entry — latency-bound with zero
// TLP. Split it 9x over (gaussian, txi, tyi): grid dim3(gblocks, 9); max bbox
// width 14 voxels => <=3 tiles/axis, so (txi,tyi) in [0,3)^2 covers all
// (tx,ty); only the tz loop (<=3 iters) stays serial per thread.
// ws use ~96.2 MB (harness d_ws is 256 MiB per its 0xAA poison fill).
// ---------------------------------------------------------------------------

#define NTILE 32768           // 32^3 tiles of 8^3 voxels
#define CAP   48              // avg ~15.3 pairs/tile (lambda+8 sigma)
#define LOG2E 1.4426950408889634f

typedef unsigned long long ull;

struct __align__(16) Pair {   // 64 B
    unsigned mlo, mhi;        // 64-bit (ly,lz) validity mask, bit = ly*8+lz
    float cy, cz, w2;         // voxel-space center (y,z), exp2 scale
    float ex[8];              // x-table: inten*exp2(dx^2*w2), zeroed outside clip
    unsigned pad[3];
};

// ---- kernel 1: per-(Gaussian, tx, ty) precompute + binning -----------------
__global__ __launch_bounds__(256) void bin_prep_kernel(
    const float* __restrict__ centers,
    const float* __restrict__ sigmas,
    const float* __restrict__ intens,
    int*  __restrict__ counts,
    Pair* __restrict__ list,
    int N)
{
    int g = blockIdx.x * 256 + threadIdx.x;
    if (g >= N) return;
    int txi = blockIdx.y % 3;          // wave-uniform
    int tyi = blockIdx.y / 3;

    float cx = centers[3*g+0] * 255.0f;
    float cy = centers[3*g+1] * 255.0f;
    float cz = centers[3*g+2] * 255.0f;
    float sig = sigmas[g];
    float cut = 3.0f * sig * 255.0f;
    float cc[3] = {cx, cy, cz};
    int mn[3], mx[3];
    #pragma unroll
    for (int a = 0; a < 3; ++a) {
        mn[a] = (int)floorf(fmaxf(cc[a] - cut, 0.0f));
        mx[a] = (int)fminf(floorf(fminf(cc[a] + cut, 255.0f)) + 1.0f, 256.0f); // exclusive
    }
    float s255 = sig * 255.0f;
    float w2 = -0.5f * LOG2E / (s255 * s255);
    float inten = intens[g];

    int t0x = mn[0] >> 3, t1x = (mx[0] - 1) >> 3;
    int t0y = mn[1] >> 3, t1y = (mx[1] - 1) >> 3;
    int t0z = mn[2] >> 3, t1z = (mx[2] - 1) >> 3;

    int tx = t0x + txi; if (tx > t1x) return;
    int ty = t0y + tyi; if (ty > t1y) return;

    int ox = tx << 3;
    int lox = max(mn[0] - ox, 0), hix = min(mx[0] - ox, 8);
    // clipped, intensity-folded x-table
    float ex[8];
    #pragma unroll
    for (int i = 0; i < 8; ++i) {
        float d = (float)(ox + i) - cx;
        float v = exp2f(d * d * w2) * inten;
        ex[i] = (i >= lox && i < hix) ? v : 0.0f;
    }

    int oy = ty << 3;
    int loy = max(mn[1] - oy, 0), hiy = min(mx[1] - oy, 8);
    ull ym = ((~0ull) << (loy << 3)) & ((~0ull) >> (64 - (hiy << 3)));

    for (int tz = t0z; tz <= t1z; ++tz) {
        int oz = tz << 3;
        int loz = max(mn[2] - oz, 0), hiz = min(mx[2] - oz, 8);
        unsigned zpat = (0xFFu >> (8 - hiz)) & (0xFFu << loz);
        ull m = (zpat * 0x0101010101010101ull) & ym;
        int t = (tx << 10) | (ty << 5) | tz;
        int slot = atomicAdd(&counts[t], 1);
        if (slot < CAP) {
            int4* q = (int4*)&list[t * CAP + slot];
            q[0] = make_int4((int)(unsigned)m, (int)(unsigned)(m >> 32),
                             __float_as_int(cy), __float_as_int(cz));
            q[1] = make_int4(__float_as_int(w2), __float_as_int(ex[0]),
                             __float_as_int(ex[1]), __float_as_int(ex[2]));
            q[2] = make_int4(__float_as_int(ex[3]), __float_as_int(ex[4]),
                             __float_as_int(ex[5]), __float_as_int(ex[6]));
            q[3] = make_int4(__float_as_int(ex[7]), 0, 0, 0);
        }
    }
}

// ---- kernel 2: main gather — one wave per 8^3 tile, depth-3 pipeline -------
__global__ __launch_bounds__(256) void splat_main(
    const int*  __restrict__ counts,
    const Pair* __restrict__ list,
    float* __restrict__ vol)
{
    int wid = threadIdx.x >> 6;
    int t   = __builtin_amdgcn_readfirstlane(blockIdx.x * 4 + wid);
    int ox = (t >> 10) << 3, oy = ((t >> 5) & 31) << 3, oz = (t & 31) << 3;
    int lane = threadIdx.x & 63;
    int ly = lane >> 3, lz = lane & 7;

    int n = counts[t]; if (n > CAP) n = CAP;
    const Pair* base = list + t * CAP;

    float fy = (float)(oy + ly);
    float fz = (float)(oz + lz);

    float acc[8];
    #pragma unroll
    for (int i = 0; i < 8; ++i) acc[i] = 0.0f;

    auto body = [&](const Pair& p) {
        float dy = fy - p.cy, dz = fz - p.cz;
        float e  = exp2f(fmaf(dy, dy, dz * dz) * p.w2);
        ull m = ((ull)p.mhi << 32) | (ull)p.mlo;
        float em;
        asm("v_cndmask_b32 %0, 0, %1, %2" : "=v"(em) : "v"(e), "s"(m));
        #pragma unroll
        for (int i = 0; i < 8; ++i)
            acc[i] = fmaf(p.ex[i], em, acc[i]);
    };

    // depth-3 software pipeline; list is padded so overreads are in-bounds
    Pair p0 = base[0], p1 = base[1], p2 = base[2];
    int k = 0;
    for (; k + 3 <= n; k += 3) {
        Pair a = base[k + 3];
        Pair b = base[k + 4];
        Pair c = base[k + 5];
        body(p0); body(p1); body(p2);
        p0 = a; p1 = b; p2 = c;
    }
    if (k     < n) body(p0);
    if (k + 1 < n) body(p1);
    if (k + 2 < n) body(p2);

    int ybase = ((oy + ly) << 8) + (oz + lz);
    #pragma unroll
    for (int i = 0; i < 8; ++i)
        vol[((ox + i) << 16) + ybase] = acc[i];
}

// ---------------------------------------------------------------------------
extern "C" void kernel_launch(void* const* d_in, const int* in_sizes, int n_in,
                              void* d_out, int out_size, void* d_ws, size_t ws_size,
                              hipStream_t stream) {
    const float* centers = (const float*)d_in[0];   // (N,3)
    const float* sigmas  = (const float*)d_in[1];   // (N,)
    const float* intens  = (const float*)d_in[2];   // (N,)
    float* vol = (float*)d_out;                     // 256^3 fp32
    const int N = in_sizes[1];

    // workspace: counts 128KB | list (NTILE*CAP+8)*64B ~= 96.2 MB
    char* ws = (char*)d_ws;
    int*  counts = (int*)ws;
    Pair* list   = (Pair*)(ws + (size_t)NTILE * sizeof(int));

    hipMemsetAsync(counts, 0, NTILE * sizeof(int), stream);

    int gblocks = (N + 255) / 256;
    bin_prep_kernel<<<dim3(gblocks, 9), 256, 0, stream>>>(centers, sigmas, intens,
                                                          counts, list, N);
    splat_main<<<NTILE / 4, 256, 0, stream>>>(counts, list, vol);
}

// Round 2
// 124.220 us; speedup vs baseline: 1.0980x; 1.0980x over previous
//
#include <hip/hip_runtime.h>

// ---------------------------------------------------------------------------
// 3-dispatch gather splat, 8^3 tiles, one wave per tile, FAT LIST ENTRIES.
// R7: bin_prep precomputes EVERYTHING per (gaussian,tile) pair into a 64B
// record: 64-bit (y,z) lane mask, cy/cz/w2, clipped+intensity-folded 8-tap
// x-table. R8: bin_prep split 9x over (gaussian,txi,tyi).
// R9 (this round): splat_main was latency-bound (VALUBusy 29%, HBM 25%,
// VGPR=12/SGPR=80 => pair data in SGPRs via s_load; 32MB list misses the
// non-shared 4MiB/XCD L2s => ~900cy stalls; depth-3 SGPR pipeline covers
// ~90cy and SGPR budget forbids going deeper). Fix: per-wave LDS staging —
// coalesced int4 copy of the tile's pair list (64 loads in flight), then
// ds_read_b128 broadcast (uniform addr, conflict-free) + depth-2 VGPR
// pipeline. No barriers: each wave owns its LDS slice.
// ws use ~96.2 MB (harness d_ws is 256 MiB per its 0xAA poison fill).
// ---------------------------------------------------------------------------

#define NTILE 32768           // 32^3 tiles of 8^3 voxels
#define CAP   48              // avg ~15.3 pairs/tile (lambda+8 sigma)
#define LOG2E 1.4426950408889634f

typedef unsigned long long ull;

struct __align__(16) Pair {   // 64 B
    unsigned mlo, mhi;        // 64-bit (ly,lz) validity mask, bit = ly*8+lz
    float cy, cz, w2;         // voxel-space center (y,z), exp2 scale
    float ex[8];              // x-table: inten*exp2(dx^2*w2), zeroed outside clip
    unsigned pad[3];
};

// ---- kernel 1: per-(Gaussian, tx, ty) precompute + binning -----------------
__global__ __launch_bounds__(256) void bin_prep_kernel(
    const float* __restrict__ centers,
    const float* __restrict__ sigmas,
    const float* __restrict__ intens,
    int*  __restrict__ counts,
    Pair* __restrict__ list,
    int N)
{
    int g = blockIdx.x * 256 + threadIdx.x;
    if (g >= N) return;
    int txi = blockIdx.y % 3;          // wave-uniform
    int tyi = blockIdx.y / 3;

    float cx = centers[3*g+0] * 255.0f;
    float cy = centers[3*g+1] * 255.0f;
    float cz = centers[3*g+2] * 255.0f;
    float sig = sigmas[g];
    float cut = 3.0f * sig * 255.0f;
    float cc[3] = {cx, cy, cz};
    int mn[3], mx[3];
    #pragma unroll
    for (int a = 0; a < 3; ++a) {
        mn[a] = (int)floorf(fmaxf(cc[a] - cut, 0.0f));
        mx[a] = (int)fminf(floorf(fminf(cc[a] + cut, 255.0f)) + 1.0f, 256.0f); // exclusive
    }
    float s255 = sig * 255.0f;
    float w2 = -0.5f * LOG2E / (s255 * s255);
    float inten = intens[g];

    int t0x = mn[0] >> 3, t1x = (mx[0] - 1) >> 3;
    int t0y = mn[1] >> 3, t1y = (mx[1] - 1) >> 3;
    int t0z = mn[2] >> 3, t1z = (mx[2] - 1) >> 3;

    int tx = t0x + txi; if (tx > t1x) return;
    int ty = t0y + tyi; if (ty > t1y) return;

    int ox = tx << 3;
    int lox = max(mn[0] - ox, 0), hix = min(mx[0] - ox, 8);
    // clipped, intensity-folded x-table
    float ex[8];
    #pragma unroll
    for (int i = 0; i < 8; ++i) {
        float d = (float)(ox + i) - cx;
        float v = exp2f(d * d * w2) * inten;
        ex[i] = (i >= lox && i < hix) ? v : 0.0f;
    }

    int oy = ty << 3;
    int loy = max(mn[1] - oy, 0), hiy = min(mx[1] - oy, 8);
    ull ym = ((~0ull) << (loy << 3)) & ((~0ull) >> (64 - (hiy << 3)));

    for (int tz = t0z; tz <= t1z; ++tz) {
        int oz = tz << 3;
        int loz = max(mn[2] - oz, 0), hiz = min(mx[2] - oz, 8);
        unsigned zpat = (0xFFu >> (8 - hiz)) & (0xFFu << loz);
        ull m = (zpat * 0x0101010101010101ull) & ym;
        int t = (tx << 10) | (ty << 5) | tz;
        int slot = atomicAdd(&counts[t], 1);
        if (slot < CAP) {
            int4* q = (int4*)&list[t * CAP + slot];
            q[0] = make_int4((int)(unsigned)m, (int)(unsigned)(m >> 32),
                             __float_as_int(cy), __float_as_int(cz));
            q[1] = make_int4(__float_as_int(w2), __float_as_int(ex[0]),
                             __float_as_int(ex[1]), __float_as_int(ex[2]));
            q[2] = make_int4(__float_as_int(ex[3]), __float_as_int(ex[4]),
                             __float_as_int(ex[5]), __float_as_int(ex[6]));
            q[3] = make_int4(__float_as_int(ex[7]), 0, 0, 0);
        }
    }
}

// ---- kernel 2: main gather — one wave per 8^3 tile, LDS-staged pair list ---
__global__ __launch_bounds__(256) void splat_main(
    const int*  __restrict__ counts,
    const Pair* __restrict__ list,
    float* __restrict__ vol)
{
    // per-wave pair buffer: CAP+1 slots (one pad slot so depth-2 prefetch of
    // pair n is always in-bounds), 4 int4 per pair. 4 waves * 12.5 KB = 50 KB? no:
    // (CAP+1)*4 int4 = 196 int4 = 3136 B per wave -> 12.5 KB per block.
    __shared__ int4 sh[4][(CAP + 1) * 4];

    int wid = threadIdx.x >> 6;
    int lane = threadIdx.x & 63;
    int t = __builtin_amdgcn_readfirstlane(blockIdx.x * 4 + wid);
    int ox = (t >> 10) << 3, oy = ((t >> 5) & 31) << 3, oz = (t & 31) << 3;
    int ly = lane >> 3, lz = lane & 7;

    int n = counts[t]; if (n > CAP) n = CAP;
    const int4* __restrict__ src = (const int4*)(list + (size_t)t * CAP);

    // stage: coalesced per-lane int4 copy, wave-private region, no barrier.
    int nch = n << 2;
    for (int j = lane; j < nch; j += 64)
        sh[wid][j] = src[j];

    float fy = (float)(oy + ly);
    float fz = (float)(oz + lz);

    float acc[8];
    #pragma unroll
    for (int i = 0; i < 8; ++i) acc[i] = 0.0f;

    const int4* P = sh[wid];

    auto body = [&](int4 q0, int4 q1, int4 q2, int4 q3) {
        float cy = __int_as_float(q0.z), cz = __int_as_float(q0.w);
        float w2 = __int_as_float(q1.x);
        float dy = fy - cy, dz = fz - cz;
        float e  = exp2f(fmaf(dy, dy, dz * dz) * w2);
        // mask is wave-uniform; hoist to SGPR for v_cndmask
        unsigned smlo = __builtin_amdgcn_readfirstlane((unsigned)q0.x);
        unsigned smhi = __builtin_amdgcn_readfirstlane((unsigned)q0.y);
        ull m = ((ull)smhi << 32) | (ull)smlo;
        float em;
        asm("v_cndmask_b32 %0, 0, %1, %2" : "=v"(em) : "v"(e), "s"(m));
        float ex0 = __int_as_float(q1.y), ex1 = __int_as_float(q1.z);
        float ex2 = __int_as_float(q1.w), ex3 = __int_as_float(q2.x);
        float ex4 = __int_as_float(q2.y), ex5 = __int_as_float(q2.z);
        float ex6 = __int_as_float(q2.w), ex7 = __int_as_float(q3.x);
        acc[0] = fmaf(ex0, em, acc[0]);
        acc[1] = fmaf(ex1, em, acc[1]);
        acc[2] = fmaf(ex2, em, acc[2]);
        acc[3] = fmaf(ex3, em, acc[3]);
        acc[4] = fmaf(ex4, em, acc[4]);
        acc[5] = fmaf(ex5, em, acc[5]);
        acc[6] = fmaf(ex6, em, acc[6]);
        acc[7] = fmaf(ex7, em, acc[7]);
    };

    // depth-2 register pipeline over LDS (broadcast reads, conflict-free)
    int4 a0 = P[0], a1 = P[1], a2 = P[2], a3 = P[3];
    for (int k = 0; k < n; ++k) {
        int b = (k + 1) << 2;           // prefetch pair k+1 (pad slot keeps it in-bounds)
        int4 b0 = P[b+0], b1 = P[b+1], b2 = P[b+2], b3 = P[b+3];
        body(a0, a1, a2, a3);
        a0 = b0; a1 = b1; a2 = b2; a3 = b3;
    }

    int ybase = ((oy + ly) << 8) + (oz + lz);
    #pragma unroll
    for (int i = 0; i < 8; ++i)
        vol[((ox + i) << 16) + ybase] = acc[i];
}

// ---------------------------------------------------------------------------
extern "C" void kernel_launch(void* const* d_in, const int* in_sizes, int n_in,
                              void* d_out, int out_size, void* d_ws, size_t ws_size,
                              hipStream_t stream) {
    const float* centers = (const float*)d_in[0];   // (N,3)
    const float* sigmas  = (const float*)d_in[1];   // (N,)
    const float* intens  = (const float*)d_in[2];   // (N,)
    float* vol = (float*)d_out;                     // 256^3 fp32
    const int N = in_sizes[1];

    // workspace: counts 128KB | list (NTILE*CAP+8)*64B ~= 96.2 MB
    char* ws = (char*)d_ws;
    int*  counts = (int*)ws;
    Pair* list   = (Pair*)(ws + (size_t)NTILE * sizeof(int));

    hipMemsetAsync(counts, 0, NTILE * sizeof(int), stream);

    int gblocks = (N + 255) / 256;
    bin_prep_kernel<<<dim3(gblocks, 9), 256, 0, stream>>>(centers, sigmas, intens,
                                                          counts, list, N);
    splat_main<<<NTILE / 4, 256, 0, stream>>>(counts, list, vol);
}